// Round 1
// baseline (243.402 us; speedup 1.0000x reference)
//
#include <hip/hip_runtime.h>
#include <math.h>

typedef float f4 __attribute__((ext_vector_type(4)));

#define TT   2048
#define CC   768
#define HH   64
#define NB   8
#define NBT  (NB * TT)        // 16384 rows
#define NQ   (NBT * HH)       // 1048576 floats per q/k/v matrix

// ---------------------------------------------------------------------------
// Kernel 1: QKV projection.  [16384 x 768] @ [768 x 192] (q|k|v concatenated)
// Block: 256 threads, tile 64 rows x 192 cols, K staged in chunks of 32.
// Thread owns 8 rows x 6 cols (cols strided by 32 for LDS bank spread).
// ---------------------------------------------------------------------------
__global__ __launch_bounds__(256) void qkv_proj(
    const float* __restrict__ x, const float* __restrict__ Wk,
    const float* __restrict__ Wq, const float* __restrict__ Wv,
    float* __restrict__ ws) {
  __shared__ float xs[64][36];    // x tile, row-major, +4 pad (16B-aligned rows)
  __shared__ float wt[192][36];   // W tile transposed: [col][k], +4 pad
  const int tid = threadIdx.x;
  const int row0 = blockIdx.x * 64;
  const int tr = tid >> 5;        // 0..7  -> rows tr*8 + i
  const int tc = tid & 31;        // 0..31 -> cols tc + 32*j

  float acc[8][6];
#pragma unroll
  for (int i = 0; i < 8; ++i)
#pragma unroll
    for (int j = 0; j < 6; ++j) acc[i][j] = 0.f;

  for (int k0 = 0; k0 < CC; k0 += 32) {
    __syncthreads();
    // stage x tile [64 rows x 32 k]
    {
      int r = tid >> 2, kb = (tid & 3) * 8;
      const f4* src = (const f4*)(x + (size_t)(row0 + r) * CC + k0 + kb);
      f4 a = src[0], b = src[1];
      *(f4*)&xs[r][kb] = a;
      *(f4*)&xs[r][kb + 4] = b;
    }
    // stage W transposed: wt[c][k] = W_m[k0+k][c&63], c-major for coalescing
#pragma unroll
    for (int j = 0; j < 24; ++j) {
      int e = tid + 256 * j;      // 0..6143
      int c = e % 192;
      int k = e / 192;
      int m = c >> 6, col = c & 63;
      const float* Wm = (m == 0) ? Wq : (m == 1) ? Wk : Wv;
      wt[c][k] = Wm[(size_t)(k0 + k) * HH + col];
    }
    __syncthreads();
#pragma unroll
    for (int kk = 0; kk < 8; ++kk) {      // 4 k-values per step
      f4 xv[8], wv[6];
#pragma unroll
      for (int i = 0; i < 8; ++i) xv[i] = *(const f4*)&xs[tr * 8 + i][kk * 4];
#pragma unroll
      for (int j = 0; j < 6; ++j) wv[j] = *(const f4*)&wt[tc + 32 * j][kk * 4];
#pragma unroll
      for (int i = 0; i < 8; ++i)
#pragma unroll
        for (int j = 0; j < 6; ++j)
#pragma unroll
          for (int u = 0; u < 4; ++u) acc[i][j] += xv[i][u] * wv[j][u];
    }
  }
  // write q/k/v to workspace: ws[0]=q, ws[NQ]=k, ws[2NQ]=v
#pragma unroll
  for (int j = 0; j < 6; ++j) {
    int c = tc + 32 * j;
    int m = c >> 6, h = c & 63;
    float* dst = ws + (size_t)m * NQ;
#pragma unroll
    for (int i = 0; i < 8; ++i)
      dst[(size_t)(row0 + tr * 8 + i) * HH + h] = acc[i][j];
  }
}

// ---------------------------------------------------------------------------
// Kernel 2: flash-style causal attention, fp32.
// Grid: 512 blocks = 8 batches x 64 q-tiles of 32 rows, heavy tiles first.
// Block: 256 threads; thread owns 2 q-rows x 4 kv-cols (S) / 4 h-cols (O).
// KV tile = 64.  Online softmax with per-16-lane shuffle reduction.
// ---------------------------------------------------------------------------
__global__ __launch_bounds__(256) void attn(
    const float* __restrict__ ws, float* __restrict__ out) {
  const float* qw = ws;
  const float* kw = ws + NQ;
  const float* vw = ws + 2 * (size_t)NQ;

  __shared__ float Qs[32][68];   // +4 pad
  __shared__ float Ks[64][64];   // XOR-swizzled float4 slots within row
  __shared__ float Vs[64][64];   // linear
  __shared__ float Ps[32][68];   // +4 pad

  const int tid = threadIdx.x;
  const int bid = blockIdx.x;
  const int b  = bid & 7;
  const int qt = 63 - (bid >> 3);      // heavy (large qt) tiles dispatch first
  const int q0 = qt * 32;
  const int tq = tid >> 4;             // 0..15 -> q rows tq*2 + i
  const int tc = tid & 15;             // 0..15 -> kv cols tc + 16*j, h cols tc*4 + j

  // stage Q tile, pre-scaled by H^-0.5 = 0.125 (exact power of two)
  {
    int r = tid >> 3;                  // 0..31
    int c4 = tid & 7;                  // two float4s: c4, c4+8
    const f4* src = (const f4*)(qw + (size_t)(b * TT + q0 + r) * HH);
    f4 a = src[c4];
    f4 b2 = src[c4 + 8];
    a *= 0.125f;
    b2 *= 0.125f;
    *(f4*)&Qs[r][c4 * 4] = a;
    *(f4*)&Qs[r][c4 * 4 + 32] = b2;
  }

  float m_i[2] = {-INFINITY, -INFINITY};
  float l_i[2] = {0.f, 0.f};
  float o[2][4];
#pragma unroll
  for (int i = 0; i < 2; ++i)
#pragma unroll
    for (int j = 0; j < 4; ++j) o[i][j] = 0.f;

  const int nk = (q0 >> 6) + 1;        // kv tiles of 64 needed (causal)
  for (int kt = 0; kt < nk; ++kt) {
    const int kv0 = kt << 6;
    __syncthreads();
    // stage K (swizzled) and V tiles [64 x 64]
    {
      int rr = tid >> 4;               // 0..15
      int c4 = tid & 15;               // float4 column slot
#pragma unroll
      for (int jj = 0; jj < 4; ++jj) {
        int row = rr + 16 * jj;
        size_t gbase = (size_t)(b * TT + kv0 + row) * HH + c4 * 4;
        f4 kv4 = *(const f4*)(kw + gbase);
        f4 vv4 = *(const f4*)(vw + gbase);
        int slot = c4 ^ (row & 7);
        *(f4*)&Ks[row][slot * 4] = kv4;
        *(f4*)&Vs[row][c4 * 4] = vv4;
      }
    }
    __syncthreads();

    // S = Q . K^T   (Q pre-scaled)
    float s[2][4];
#pragma unroll
    for (int i = 0; i < 2; ++i)
#pragma unroll
      for (int j = 0; j < 4; ++j) s[i][j] = 0.f;
#pragma unroll
    for (int kk = 0; kk < 16; ++kk) {
      f4 qv[2], kv4[4];
#pragma unroll
      for (int i = 0; i < 2; ++i) qv[i] = *(const f4*)&Qs[tq * 2 + i][kk * 4];
#pragma unroll
      for (int j = 0; j < 4; ++j) {
        int c = tc + 16 * j;
        kv4[j] = *(const f4*)&Ks[c][(kk ^ (c & 7)) * 4];
      }
#pragma unroll
      for (int i = 0; i < 2; ++i)
#pragma unroll
        for (int j = 0; j < 4; ++j)
#pragma unroll
          for (int u = 0; u < 4; ++u) s[i][j] += qv[i][u] * kv4[j][u];
    }

    // causal mask (only the diagonal-overlapping last tile needs it)
    if (kt == nk - 1) {
#pragma unroll
      for (int i = 0; i < 2; ++i)
#pragma unroll
        for (int j = 0; j < 4; ++j)
          if (kv0 + tc + 16 * j > q0 + tq * 2 + i) s[i][j] = -INFINITY;
    }

    // online softmax per q-row; reduce across the 16 lanes sharing tq
#pragma unroll
    for (int i = 0; i < 2; ++i) {
      float mx = fmaxf(fmaxf(s[i][0], s[i][1]), fmaxf(s[i][2], s[i][3]));
      mx = fmaxf(mx, __shfl_xor(mx, 1));
      mx = fmaxf(mx, __shfl_xor(mx, 2));
      mx = fmaxf(mx, __shfl_xor(mx, 4));
      mx = fmaxf(mx, __shfl_xor(mx, 8));
      float mn = fmaxf(m_i[i], mx);
      float f = __expf(m_i[i] - mn);   // first tile: exp(-inf - finite) = 0
      m_i[i] = mn;
      float rs = 0.f;
#pragma unroll
      for (int j = 0; j < 4; ++j) {
        float p = __expf(s[i][j] - mn);  // masked: exp(-inf) = 0
        s[i][j] = p;
        rs += p;
      }
      rs += __shfl_xor(rs, 1);
      rs += __shfl_xor(rs, 2);
      rs += __shfl_xor(rs, 4);
      rs += __shfl_xor(rs, 8);
      l_i[i] = l_i[i] * f + rs;
#pragma unroll
      for (int j = 0; j < 4; ++j) o[i][j] *= f;
#pragma unroll
      for (int j = 0; j < 4; ++j) Ps[tq * 2 + i][tc + 16 * j] = s[i][j];
    }
    __syncthreads();

    // O += P . V
#pragma unroll
    for (int kk = 0; kk < 16; ++kk) {
      f4 pv[2], vv[4];
#pragma unroll
      for (int i = 0; i < 2; ++i) pv[i] = *(const f4*)&Ps[tq * 2 + i][kk * 4];
#pragma unroll
      for (int u = 0; u < 4; ++u) vv[u] = *(const f4*)&Vs[kk * 4 + u][tc * 4];
#pragma unroll
      for (int i = 0; i < 2; ++i)
#pragma unroll
        for (int u = 0; u < 4; ++u)
#pragma unroll
          for (int j = 0; j < 4; ++j) o[i][j] += pv[i][u] * vv[u][j];
    }
  }

  // epilogue: normalize and store
#pragma unroll
  for (int i = 0; i < 2; ++i) {
    float inv = 1.0f / l_i[i];
    f4 r;
#pragma unroll
    for (int j = 0; j < 4; ++j) r[j] = o[i][j] * inv;
    *(f4*)(out + (size_t)(b * TT + q0 + tq * 2 + i) * HH + tc * 4) = r;
  }
}

extern "C" void kernel_launch(void* const* d_in, const int* in_sizes, int n_in,
                              void* d_out, int out_size, void* d_ws, size_t ws_size,
                              hipStream_t stream) {
  (void)in_sizes; (void)n_in; (void)out_size; (void)ws_size;
  const float* x  = (const float*)d_in[0];
  const float* Wk = (const float*)d_in[1];
  const float* Wq = (const float*)d_in[2];
  const float* Wv = (const float*)d_in[3];
  float* ws = (float*)d_ws;          // q | k | v, 4 MB each (12 MB total)
  float* op = (float*)d_out;

  hipLaunchKernelGGL(qkv_proj, dim3(NBT / 64), dim3(256), 0, stream,
                     x, Wk, Wq, Wv, ws);
  hipLaunchKernelGGL(attn, dim3(NB * (TT / 32)), dim3(256), 0, stream,
                     ws, op);
}

// Round 2
// 81.197 us; speedup vs baseline: 2.9977x; 2.9977x over previous
//
#include <hip/hip_runtime.h>
#include <math.h>

typedef float f4 __attribute__((ext_vector_type(4)));
typedef float f32x4 __attribute__((ext_vector_type(4)));
typedef short s8v __attribute__((ext_vector_type(8)));
typedef unsigned short u16;
typedef u16 u16x4 __attribute__((ext_vector_type(4)));

#define TT 2048
#define CC 768
#define HH 64
#define NB 8
#define NBT (NB * TT)
#define NQ (NBT * HH)

__device__ __forceinline__ u16 f2bf(float f) {
  unsigned u = __float_as_uint(f);
  u = (u + 0x7fffu + ((u >> 16) & 1u)) >> 16;
  return (u16)u;
}

#define MFMA16(a, b, c) __builtin_amdgcn_mfma_f32_16x16x32_bf16(a, b, c, 0, 0, 0)

// ---------------------------------------------------------------------------
// Kernel 0: W -> bf16, transposed: wt[c][kc], c: 0..63=q, 64..127=k, 128..191=v
// ---------------------------------------------------------------------------
__global__ __launch_bounds__(256) void prep_w(
    const float* __restrict__ Wk, const float* __restrict__ Wq,
    const float* __restrict__ Wv, u16* __restrict__ wt) {
  int idx = blockIdx.x * 256 + threadIdx.x;   // 0..147455
  int c = idx / CC, kc = idx % CC;
  const float* Wm = (c < 64) ? Wq : (c < 128) ? Wk : Wv;
  wt[idx] = f2bf(Wm[kc * HH + (c & 63)]);
}

// ---------------------------------------------------------------------------
// Kernel 1: QKV projection, bf16 MFMA. 64 rows x 192 cols per block.
// 4 waves, each 32 rows x 96 cols. Outputs: qb (x0.125), kb, vt (v transposed).
// LDS: xs swizzled [64][64]bf16 @0, wt swizzled [192][64]bf16 @8192.
// ---------------------------------------------------------------------------
__global__ __launch_bounds__(256) void qkv_proj(
    const float* __restrict__ x, const u16* __restrict__ wt,
    u16* __restrict__ qb, u16* __restrict__ kb, u16* __restrict__ vt) {
  __shared__ char lds[32768];
  const int tid = threadIdx.x;
  const int wv = tid >> 6, lane = tid & 63;
  const int g = lane >> 4, t16 = lane & 15;
  const int wr = wv >> 1, wc = wv & 1;
  const int row0 = blockIdx.x * 64;

  f32x4 zz = {0.f, 0.f, 0.f, 0.f};
  f32x4 acc[2][6];
#pragma unroll
  for (int am = 0; am < 2; ++am)
#pragma unroll
    for (int cf = 0; cf < 6; ++cf) acc[am][cf] = zz;

  for (int kt = 0; kt < 12; ++kt) {
    const int k0 = kt * 64;
    __syncthreads();
    // stage x (fp32 global -> bf16 LDS, XOR-swizzled)
#pragma unroll
    for (int n = 0; n < 4; ++n) {
      int e = n * 256 + tid;
      int row = e >> 4, c4 = e & 15;
      f4 xv = *(const f4*)(x + (size_t)(row0 + row) * CC + k0 + c4 * 4);
      u16x4 xb;
#pragma unroll
      for (int u = 0; u < 4; ++u) xb[u] = f2bf(xv[u]);
      int off = (row * 128 + c4 * 8) ^ ((row & 7) << 4);
      *(u16x4*)(lds + off) = xb;
    }
    // stage wt via global_load_lds, source pre-swizzled (linear LDS dest)
#pragma unroll
    for (int n = 0; n < 6; ++n) {
      int idx = n * 256 + tid;
      int row = idx >> 3, slot = idx & 7;
      const u16* src = wt + (size_t)row * CC + k0 + ((slot ^ (row & 7)) << 3);
      char* dst = lds + 8192 + n * 4096 + wv * 1024;
      __builtin_amdgcn_global_load_lds((const unsigned int*)src,
                                       (unsigned int*)dst, 16, 0, 0);
    }
    asm volatile("s_waitcnt vmcnt(0)" ::: "memory");
    __syncthreads();
    // compute: per wave 2x6 fragments, K-step 32 x2
#pragma unroll
    for (int s = 0; s < 2; ++s) {
      s8v a[2], bb[6];
#pragma unroll
      for (int am = 0; am < 2; ++am) {
        int row = wr * 32 + am * 16 + t16;
        int off = (row * 128 + s * 64 + g * 16) ^ ((row & 7) << 4);
        a[am] = *(const s8v*)(lds + off);
      }
#pragma unroll
      for (int cf = 0; cf < 6; ++cf) {
        int col = wc * 96 + cf * 16 + t16;
        int off = 8192 + ((col * 128 + s * 64 + g * 16) ^ ((col & 7) << 4));
        bb[cf] = *(const s8v*)(lds + off);
      }
#pragma unroll
      for (int am = 0; am < 2; ++am)
#pragma unroll
        for (int cf = 0; cf < 6; ++cf)
          acc[am][cf] = MFMA16(a[am], bb[cf], acc[am][cf]);
    }
  }
  // epilogue: D layout col=lane&15, row=(lane>>4)*4+reg
#pragma unroll
  for (int am = 0; am < 2; ++am) {
    int rb = row0 + wr * 32 + am * 16 + g * 4;
#pragma unroll
    for (int cf = 0; cf < 6; ++cf) {
      int col = wc * 96 + cf * 16 + t16;
      int m = col >> 6, h = col & 63;
      if (m == 0) {
#pragma unroll
        for (int r = 0; r < 4; ++r)
          qb[(size_t)(rb + r) * HH + h] = f2bf(acc[am][cf][r] * 0.125f);
      } else if (m == 1) {
#pragma unroll
        for (int r = 0; r < 4; ++r)
          kb[(size_t)(rb + r) * HH + h] = f2bf(acc[am][cf][r]);
      } else {
        int bbi = rb >> 11, t = rb & 2047;
        u16x4 vvv;
#pragma unroll
        for (int r = 0; r < 4; ++r) vvv[r] = f2bf(acc[am][cf][r]);
        *(u16x4*)(vt + (size_t)(bbi * 64 + h) * TT + t) = vvv;
      }
    }
  }
}

// ---------------------------------------------------------------------------
// Kernel 2: flash attention, bf16 MFMA. QBLK=32 (2 waves x 16 rows), KVBLK=64.
// K/V double-buffered swizzled LDS via global_load_lds (pre-swizzled source).
// LDS: K 2x8KB @0, V 2x8KB @16384, P per-wave 2KB @32768.
// ---------------------------------------------------------------------------
__global__ __launch_bounds__(128) void attn(
    const u16* __restrict__ qb, const u16* __restrict__ kb,
    const u16* __restrict__ vt, float* __restrict__ out) {
  __shared__ char lds[36864];
  const int tid = threadIdx.x;
  const int wv = tid >> 6, lane = tid & 63;
  const int g = lane >> 4, t16 = lane & 15;
  const int bid = blockIdx.x;
  const int b = bid & 7;                 // = XCD id under default round-robin
  const int qt = 63 - (bid >> 3);        // heavy tiles first
  const int q0 = qt * 32;
  const size_t bT = (size_t)b * TT;
  const int b64 = b * 64;

  // Q fragments in registers (qb pre-scaled by 0.125)
  s8v qf[2];
#pragma unroll
  for (int s = 0; s < 2; ++s)
    qf[s] = *(const s8v*)(qb + (bT + q0 + wv * 16 + t16) * HH + s * 32 + g * 8);

  const int nk = (q0 >> 6) + 1;

  auto stage = [&](int bufb, int kt) {
    int kv0 = kt * 64;
#pragma unroll
    for (int n = 0; n < 4; ++n) {
      int idx = n * 128 + tid;
      int row = idx >> 3, slot = idx & 7;
      int hsw = (slot ^ (row & 7)) << 3;
      const u16* srcK = kb + (bT + kv0 + row) * HH + hsw;
      const u16* srcV = vt + (size_t)(b64 + row) * TT + kv0 + hsw;
      char* dK = lds + bufb * 8192 + n * 2048 + wv * 1024;
      char* dV = lds + 16384 + bufb * 8192 + n * 2048 + wv * 1024;
      __builtin_amdgcn_global_load_lds((const unsigned int*)srcK,
                                       (unsigned int*)dK, 16, 0, 0);
      __builtin_amdgcn_global_load_lds((const unsigned int*)srcV,
                                       (unsigned int*)dV, 16, 0, 0);
    }
  };

  stage(0, 0);

  float m_i[4] = {-INFINITY, -INFINITY, -INFINITY, -INFINITY};
  float l_i[4] = {0.f, 0.f, 0.f, 0.f};
  f32x4 zz = {0.f, 0.f, 0.f, 0.f};
  f32x4 oa[4] = {zz, zz, zz, zz};

  asm volatile("s_waitcnt vmcnt(0)" ::: "memory");
  __syncthreads();

  int cur = 0;
  for (int kt = 0; kt < nk; ++kt) {
    if (kt + 1 < nk) stage(cur ^ 1, kt + 1);   // prefetch overlaps compute

    // S = Q . K^T  (16 q-rows x 64 kv-cols per wave)
    f32x4 sa[4] = {zz, zz, zz, zz};
#pragma unroll
    for (int s = 0; s < 2; ++s)
#pragma unroll
      for (int c = 0; c < 4; ++c) {
        int row = c * 16 + t16;
        int off = cur * 8192 + ((row * 128 + s * 64 + g * 16) ^ ((row & 7) << 4));
        s8v kf = *(const s8v*)(lds + off);
        sa[c] = MFMA16(qf[s], kf, sa[c]);
      }

    if (kt == nk - 1) {
      int kv0 = kt * 64;
#pragma unroll
      for (int c = 0; c < 4; ++c) {
        int col = kv0 + c * 16 + t16;
#pragma unroll
        for (int r = 0; r < 4; ++r)
          if (col > q0 + wv * 16 + g * 4 + r) sa[c][r] = -INFINITY;
      }
    }

    // online softmax: rows (lane>>4)*4+r; cols across lane&15 x 4 accs
#pragma unroll
    for (int r = 0; r < 4; ++r) {
      float mx = fmaxf(fmaxf(sa[0][r], sa[1][r]), fmaxf(sa[2][r], sa[3][r]));
      mx = fmaxf(mx, __shfl_xor(mx, 1));
      mx = fmaxf(mx, __shfl_xor(mx, 2));
      mx = fmaxf(mx, __shfl_xor(mx, 4));
      mx = fmaxf(mx, __shfl_xor(mx, 8));
      float mn = fmaxf(m_i[r], mx);
      float fr = __expf(m_i[r] - mn);
      m_i[r] = mn;
      float rs = 0.f;
#pragma unroll
      for (int c = 0; c < 4; ++c) {
        float p = __expf(sa[c][r] - mn);
        sa[c][r] = p;
        rs += p;
      }
      rs += __shfl_xor(rs, 1);
      rs += __shfl_xor(rs, 2);
      rs += __shfl_xor(rs, 4);
      rs += __shfl_xor(rs, 8);
      l_i[r] = l_i[r] * fr + rs;
#pragma unroll
      for (int c = 0; c < 4; ++c) oa[c][r] *= fr;
    }

    // P -> wave-local LDS (bf16, swizzled); re-read as A-fragments
#pragma unroll
    for (int c = 0; c < 4; ++c)
#pragma unroll
      for (int r = 0; r < 4; ++r) {
        int row = g * 4 + r;
        int off = 32768 + wv * 2048 +
                  ((row * 128 + (c * 16 + t16) * 2) ^ ((row & 7) << 4));
        *(u16*)(lds + off) = f2bf(sa[c][r]);
      }

    // O += P . V
#pragma unroll
    for (int s2 = 0; s2 < 2; ++s2) {
      int poff = 32768 + wv * 2048 +
                 ((t16 * 128 + s2 * 64 + g * 16) ^ ((t16 & 7) << 4));
      s8v pf = *(const s8v*)(lds + poff);
#pragma unroll
      for (int c = 0; c < 4; ++c) {
        int rowh = c * 16 + t16;
        int voff = 16384 + cur * 8192 +
                   ((rowh * 128 + s2 * 64 + g * 16) ^ ((rowh & 7) << 4));
        s8v vf = *(const s8v*)(lds + voff);
        oa[c] = MFMA16(pf, vf, oa[c]);
      }
    }

    asm volatile("s_waitcnt vmcnt(0)" ::: "memory");
    __syncthreads();
    cur ^= 1;
  }

  // epilogue: normalize, store fp32
#pragma unroll
  for (int r = 0; r < 4; ++r) {
    float inv = 1.0f / l_i[r];
    size_t rowo = (bT + q0 + wv * 16 + g * 4 + r) * HH;
#pragma unroll
    for (int c = 0; c < 4; ++c)
      out[rowo + c * 16 + t16] = oa[c][r] * inv;
  }
}

extern "C" void kernel_launch(void* const* d_in, const int* in_sizes, int n_in,
                              void* d_out, int out_size, void* d_ws, size_t ws_size,
                              hipStream_t stream) {
  (void)in_sizes; (void)n_in; (void)out_size; (void)ws_size;
  const float* x  = (const float*)d_in[0];
  const float* Wk = (const float*)d_in[1];
  const float* Wq = (const float*)d_in[2];
  const float* Wv = (const float*)d_in[3];
  u16* qb = (u16*)d_ws;          // [16384][64] bf16, pre-scaled
  u16* kb = qb + NQ;             // [16384][64] bf16
  u16* vt = kb + NQ;             // [8][64][2048] bf16 (v transposed)
  u16* wt = vt + NQ;             // [192][768] bf16
  float* op = (float*)d_out;

  hipLaunchKernelGGL(prep_w, dim3(576), dim3(256), 0, stream, Wk, Wq, Wv, wt);
  hipLaunchKernelGGL(qkv_proj, dim3(NBT / 64), dim3(256), 0, stream,
                     x, wt, qb, kb, vt);
  hipLaunchKernelGGL(attn, dim3(NB * 64), dim3(128), 0, stream,
                     qb, kb, vt, op);
}